// Round 6
// baseline (803.229 us; speedup 1.0000x reference)
//
#include <hip/hip_runtime.h>

typedef unsigned short u16;
typedef unsigned int u32;
typedef __attribute__((ext_vector_type(8))) short bf16x8;
typedef __attribute__((ext_vector_type(4))) float f32x4;

#define NN 50000
#define NE 640000

// ---- bf16 helpers (bf16 -> f32 exact: shift<<16; f32 -> bf16 RNE) ----
__device__ __forceinline__ float bfl(u32 u) { return __uint_as_float(u << 16); }
__device__ __forceinline__ float bfh(u32 u) { return __uint_as_float(u & 0xffff0000u); }
__device__ __forceinline__ float bf1(u16 v) { return __uint_as_float(((u32)v) << 16); }
__device__ __forceinline__ u16 f2bf(float f) {
  u32 u = __float_as_uint(f);
  u32 r = (u + 0x7fffu + ((u >> 16) & 1u)) >> 16;
  return (u16)r;
}

// ---------------- dtype probe ----------------
__global__ void probe_kernel(const u16* __restrict__ x, const int* __restrict__ ei,
                             int* __restrict__ flags) {
  __shared__ int s_f32, s_i32;
  if (threadIdx.x == 0) { s_f32 = 0; s_i32 = 0; }
  __syncthreads();
  int lf = 0, li = 0;
  for (int i = threadIdx.x; i < 8192; i += 256) {
    float v = bf1(x[i]);
    if (!(fabsf(v) < 1e8f)) lf = 1;
    if (ei[2 * i + 1] != 0) li = 1;
  }
  if (lf) s_f32 = 1;
  if (li) s_i32 = 1;
  __syncthreads();
  if (threadIdx.x == 0) {
    flags[0] = s_f32;
    flags[1] = s_i32 ? 0 : 1;
  }
}

// ---------------- CSR build ----------------
__device__ __forceinline__ int edge_val(const int* __restrict__ w, long j, int i64) {
  return i64 ? w[2 * j] : w[j];
}

__global__ void count_kernel(const int* __restrict__ ei, const int* __restrict__ flags,
                             int* __restrict__ cnt, int E) {
  int e = blockIdx.x * blockDim.x + threadIdx.x;
  if (e >= E) return;
  int d = edge_val(ei, (long)E + e, flags[1]);
  if ((u32)d < (u32)NN) atomicAdd(&cnt[d], 1);
}

__global__ void scan_local(const int* __restrict__ cnt, int* __restrict__ excl,
                           int* __restrict__ bsum, int n) {
  __shared__ int sd[256];
  int t = threadIdx.x;
  int g = blockIdx.x * 256 + t;
  int v = (g < n) ? cnt[g] : 0;
  sd[t] = v;
  __syncthreads();
  for (int off = 1; off < 256; off <<= 1) {
    int x = (t >= off) ? sd[t - off] : 0;
    __syncthreads();
    sd[t] += x;
    __syncthreads();
  }
  int incl = sd[t];
  if (g < n) excl[g] = incl - v;
  if (t == 255) bsum[blockIdx.x] = incl;
}

__global__ void scan_totals(const int* __restrict__ bsum, int* __restrict__ boff, int nb) {
  __shared__ int sd[256];
  int t = threadIdx.x;
  int v = (t < nb) ? bsum[t] : 0;
  sd[t] = v;
  __syncthreads();
  for (int off = 1; off < 256; off <<= 1) {
    int x = (t >= off) ? sd[t - off] : 0;
    __syncthreads();
    sd[t] += x;
    __syncthreads();
  }
  if (t < nb) boff[t] = sd[t] - v;
}

__global__ void scan_add(const int* __restrict__ excl, const int* __restrict__ boff,
                         const int* __restrict__ cnt, int* __restrict__ rowptr,
                         int* __restrict__ fillp, int n) {
  int g = blockIdx.x * 256 + threadIdx.x;
  if (g < n) {
    int e2 = excl[g] + boff[blockIdx.x];
    rowptr[g] = e2;
    fillp[g] = e2;
    if (g == n - 1) rowptr[n] = e2 + cnt[g];
  }
}

__global__ void fill_kernel(const int* __restrict__ ei, const int* __restrict__ flags,
                            int* __restrict__ fillp, int* __restrict__ col,
                            int* __restrict__ dstc, int E) {
  int e = blockIdx.x * blockDim.x + threadIdx.x;
  if (e >= E) return;
  int i64 = flags[1];
  int s = edge_val(ei, (long)e, i64);
  int d = edge_val(ei, (long)E + e, i64);
  if ((u32)d >= (u32)NN) return;
  int p = atomicAdd(&fillp[d], 1);
  col[p] = ((u32)s < (u32)NN) ? s : 0;
  dstc[p] = d;
}

// ---------------- weight pre-transpose: Wt[j][k] = W[k][j], output bf16 ----------------
__global__ void transpose_w(const void* W0, const void* W1, const void* W2,
                            const void* W3, const void* W4, const void* W5,
                            u16* T0, u16* T1, u16* T2, u16* T3, u16* T4, u16* T5,
                            const int* __restrict__ flags) {
  int y = blockIdx.y;
  int M = (y < 3) ? 128 : 256;
  int flat = blockIdx.x * 256 + threadIdx.x;
  if (flat >= M * 128) return;
  int j = flat >> 7;
  int k = flat & 127;
  const void* W = (y == 0) ? W0 : (y == 1) ? W1 : (y == 2) ? W2 : (y == 3) ? W3 : (y == 4) ? W4 : W5;
  u16* T = (y == 0) ? T0 : (y == 1) ? T1 : (y == 2) ? T2 : (y == 3) ? T3 : (y == 4) ? T4 : T5;
  u16 v;
  if (flags[0])
    v = f2bf(((const float*)W)[(size_t)k * M + j]);
  else
    v = ((const u16*)W)[(size_t)k * M + j];
  T[(size_t)j * 128 + k] = v;
}

// ---------------- MFMA GEMM (unchanged) ----------------
#define LSTR 136
__global__ __launch_bounds__(256) void gemm3_mfma(
    const void* __restrict__ X,
    const u16* __restrict__ Wta, const u16* __restrict__ Wtb, const u16* __restrict__ Wtc,
    const void* __restrict__ bias,
    u16* __restrict__ Ya, u16* __restrict__ Yb, u16* __restrict__ Yc,
    const int* __restrict__ flags, int x_follows, int N, int M) {
  __shared__ __align__(16) u16 Xs[64 * LSTR];
  __shared__ __align__(16) u16 Bs[128 * LSTR];
  const int K = 128;
  int t = threadIdx.x;
  int lane = t & 63;
  int w = t >> 6;
  int n0g = blockIdx.x * 64;
  int c0 = blockIdx.z * 128;
  int F32X = x_follows ? flags[0] : 0;
  const u16* Wt = (blockIdx.y == 0) ? Wta : ((blockIdx.y == 1) ? Wtb : Wtc);
  u16* Y = (blockIdx.y == 0) ? Ya : ((blockIdx.y == 1) ? Yb : Yc);

  if (!F32X) {
    const u16* Xg = (const u16*)X;
    for (int it = 0; it < 4; ++it) {
      int i = t + 256 * it;
      int r = i >> 4, c8 = (i & 15) * 8;
      int n = n0g + r;
      uint4 v = make_uint4(0, 0, 0, 0);
      if (n < N) v = *(const uint4*)(Xg + (size_t)n * K + c8);
      *(uint4*)(Xs + r * LSTR + c8) = v;
    }
  } else {
    const float* Xg = (const float*)X;
    for (int it = 0; it < 4; ++it) {
      int i = t + 256 * it;
      int r = i >> 4, c8 = (i & 15) * 8;
      int n = n0g + r;
      uint4 pk = make_uint4(0, 0, 0, 0);
      if (n < N) {
        float4 f0 = *(const float4*)(Xg + (size_t)n * K + c8);
        float4 f1 = *(const float4*)(Xg + (size_t)n * K + c8 + 4);
        pk.x = (u32)f2bf(f0.x) | ((u32)f2bf(f0.y) << 16);
        pk.y = (u32)f2bf(f0.z) | ((u32)f2bf(f0.w) << 16);
        pk.z = (u32)f2bf(f1.x) | ((u32)f2bf(f1.y) << 16);
        pk.w = (u32)f2bf(f1.z) | ((u32)f2bf(f1.w) << 16);
      }
      *(uint4*)(Xs + r * LSTR + c8) = pk;
    }
  }
  for (int it = 0; it < 8; ++it) {
    int i = t + 256 * it;
    int j = i >> 4, k8 = (i & 15) * 8;
    uint4 v = *(const uint4*)(Wt + (size_t)(c0 + j) * K + k8);
    *(uint4*)(Bs + j * LSTR + k8) = v;
  }
  __syncthreads();

  int m0 = (w >> 1) * 32;
  int n0 = (w & 1) * 64;
  int l15 = lane & 15;
  int q8 = (lane >> 4) * 8;
  f32x4 acc[2][4];
#pragma unroll
  for (int i = 0; i < 2; ++i)
#pragma unroll
    for (int j = 0; j < 4; ++j) acc[i][j] = (f32x4){0.f, 0.f, 0.f, 0.f};

#pragma unroll
  for (int kc = 0; kc < 4; ++kc) {
    int ko = kc * 32 + q8;
    bf16x8 a[2], b[4];
#pragma unroll
    for (int i = 0; i < 2; ++i)
      a[i] = *(const bf16x8*)(Xs + (m0 + i * 16 + l15) * LSTR + ko);
#pragma unroll
    for (int j = 0; j < 4; ++j)
      b[j] = *(const bf16x8*)(Bs + (n0 + j * 16 + l15) * LSTR + ko);
#pragma unroll
    for (int i = 0; i < 2; ++i)
#pragma unroll
      for (int j = 0; j < 4; ++j)
        acc[i][j] = __builtin_amdgcn_mfma_f32_16x16x32_bf16(a[i], b[j], acc[i][j], 0, 0, 0);
  }
  __syncthreads();

  float bv[4] = {0.f, 0.f, 0.f, 0.f};
  if (blockIdx.y == 2) {
    int F32 = flags[0];
#pragma unroll
    for (int j = 0; j < 4; ++j) {
      int c = c0 + n0 + j * 16 + l15;
      bv[j] = F32 ? ((const float*)bias)[c] : bf1(((const u16*)bias)[c]);
    }
  }

  u16* Ct = Xs;
#pragma unroll
  for (int i = 0; i < 2; ++i)
#pragma unroll
    for (int j = 0; j < 4; ++j) {
      int col = n0 + j * 16 + l15;
      int rbase = m0 + i * 16 + (lane >> 4) * 4;
#pragma unroll
      for (int r = 0; r < 4; ++r)
        Ct[(rbase + r) * LSTR + col] = f2bf(acc[i][j][r] + bv[j]);
    }
  __syncthreads();

  for (int it = 0; it < 4; ++it) {
    int i = t + 256 * it;
    int r = i >> 4, c8 = (i & 15) * 8;
    int n = n0g + r;
    if (n < N) {
      uint4 v = *(const uint4*)(Ct + r * LSTR + c8);
      *(uint4*)(Y + (size_t)n * M + c0 + c8) = v;
    }
  }
}

// ---------------- per-node attention dots: A[n]=att.xl[n], B[n]=att.xr[n] ----------------
template <int F>
__global__ __launch_bounds__(256) void ab_kernel(
    const u16* __restrict__ xl, const u16* __restrict__ xr, const void* __restrict__ att,
    const int* __restrict__ flags, float* __restrict__ A, float* __restrict__ B, int N) {
  constexpr int EPL = F / 64;
  int node = blockIdx.x * 4 + (threadIdx.x >> 6);
  if (node >= N) return;
  int lane = threadIdx.x & 63;
  int base = lane * EPL;
  int F32 = flags[0];
  float attv[EPL];
#pragma unroll
  for (int e = 0; e < EPL; ++e)
    attv[e] = F32 ? ((const float*)att)[base + e] : bf1(((const u16*)att)[base + e]);
  float a = 0.f, b = 0.f;
#pragma unroll
  for (int c = 0; c < EPL / 2; ++c) {
    u32 ul = *(const u32*)(xl + (size_t)node * F + base + 2 * c);
    u32 ur = *(const u32*)(xr + (size_t)node * F + base + 2 * c);
    a = fmaf(attv[2 * c], bfl(ul), a);
    a = fmaf(attv[2 * c + 1], bfh(ul), a);
    b = fmaf(attv[2 * c], bfl(ur), b);
    b = fmaf(attv[2 * c + 1], bfh(ur), b);
  }
#pragma unroll
  for (int off = 1; off <= 32; off <<= 1) {
    a += __shfl_xor(a, off, 64);
    b += __shfl_xor(b, off, 64);
  }
  if (lane == 0) {
    A[node] = a;
    B[node] = b;
  }
}

// ---------------- edge-parallel score kernel ----------------
// w[j] = exp( 0.6*(A[col[j]]+B[dstc[j]]) + 0.4*sum_f att_f*|xl[col[j]]+xr[dstc[j]]| )
// LPE lanes per edge (LPE*8 == F), EPI = 64/LPE edges per wave. One shot, no loop.
template <int F, int LPE>
__global__ __launch_bounds__(256) void score_kernel(
    const u16* __restrict__ xl, const u16* __restrict__ xr, const void* __restrict__ att,
    const float* __restrict__ Aarr, const float* __restrict__ Barr,
    const int* __restrict__ col, const int* __restrict__ dstc,
    float* __restrict__ wout, const int* __restrict__ flags, int E) {
  constexpr int EPI = 64 / LPE;
  static_assert(LPE * 8 == F, "layout");
  int lane = threadIdx.x & 63;
  int sl = lane & (LPE - 1);
  int sub = lane / LPE;
  long wid = (long)blockIdx.x * 4 + (threadIdx.x >> 6);
  long e = wid * EPI + sub;
  bool valid = e < E;
  long ec = valid ? e : 0;
  int base = sl * 8;
  int F32 = flags[0];

  int c = col[ec];
  int d = dstc[ec];
  float pre = 0.6f * (Aarr[c] + Barr[d]);
  uint4 vl = *(const uint4*)(xl + (size_t)c * F + base);
  uint4 vr = *(const uint4*)(xr + (size_t)d * F + base);
  float attv[8];
#pragma unroll
  for (int i = 0; i < 8; ++i)
    attv[i] = F32 ? ((const float*)att)[base + i] : bf1(((const u16*)att)[base + i]);

  float r = 0.f;
  {
    float h;
    h = bfl(vl.x) + bfl(vr.x); r = fmaf(attv[0], fabsf(h), r);
    h = bfh(vl.x) + bfh(vr.x); r = fmaf(attv[1], fabsf(h), r);
    h = bfl(vl.y) + bfl(vr.y); r = fmaf(attv[2], fabsf(h), r);
    h = bfh(vl.y) + bfh(vr.y); r = fmaf(attv[3], fabsf(h), r);
    h = bfl(vl.z) + bfl(vr.z); r = fmaf(attv[4], fabsf(h), r);
    h = bfh(vl.z) + bfh(vr.z); r = fmaf(attv[5], fabsf(h), r);
    h = bfl(vl.w) + bfl(vr.w); r = fmaf(attv[6], fabsf(h), r);
    h = bfh(vl.w) + bfh(vr.w); r = fmaf(attv[7], fabsf(h), r);
  }
#pragma unroll
  for (int off = 1; off < LPE; off <<= 1) r += __shfl_xor(r, off, 64);
  float w = __expf(fmaf(0.4f, r, pre));
  if (sl == 0 && valid) wout[e] = w;
}

// ---------------- aggregation: pure weighted gather-sum per node ----------------
template <int F, int LPE, bool ELU>
__global__ __launch_bounds__(256) void agg_kernel(
    const u16* __restrict__ xl, const u16* __restrict__ res, const float* __restrict__ warr,
    const int* __restrict__ rowptr, const int* __restrict__ col,
    void* __restrict__ out, const int* __restrict__ flags, int out_follows, int N) {
  constexpr int EPI = 64 / LPE;
  static_assert(LPE * 8 == F, "layout");
  int lane = threadIdx.x & 63;
  int sl = lane & (LPE - 1);
  int sub = lane / LPE;
  int node = blockIdx.x * 4 + (threadIdx.x >> 6);
  if (node >= N) return;
  int OF32 = out_follows ? flags[0] : 0;
  int base = sl * 8;

  float acc[8];
#pragma unroll
  for (int e = 0; e < 8; ++e) acc[e] = 0.f;
  float l = 0.f;
  int beg = rowptr[node], end = rowptr[node + 1];

  for (int cs = beg; cs < end; cs += 64) {
    int n = min(64, end - cs);
    int idx = cs + lane;
    int myc = (idx < end) ? col[idx] : 0;
    float myw = (idx < end) ? warr[idx] : 0.f;
    // chunk denom sum (once per chunk)
    float ls = myw;
#pragma unroll
    for (int off = 1; off <= 32; off <<= 1) ls += __shfl_xor(ls, off, 64);
    l += ls;

    int itc = (n + EPI - 1) / EPI;
    // 2-deep pipeline
    int c0 = __shfl(myc, sub, 64);
    float w0 = __shfl(myw, sub, 64);
    uint4 v0 = *(const uint4*)(xl + (size_t)c0 * F + base);
    int c1 = 0;
    float w1 = 0.f;
    uint4 v1 = v0;
    if (itc > 1) {
      c1 = __shfl(myc, EPI + sub, 64);
      w1 = __shfl(myw, EPI + sub, 64);
      v1 = *(const uint4*)(xl + (size_t)c1 * F + base);
    }
    auto body = [&](uint4 cur, float wv) {
      acc[0] = fmaf(wv, bfl(cur.x), acc[0]);
      acc[1] = fmaf(wv, bfh(cur.x), acc[1]);
      acc[2] = fmaf(wv, bfl(cur.y), acc[2]);
      acc[3] = fmaf(wv, bfh(cur.y), acc[3]);
      acc[4] = fmaf(wv, bfl(cur.z), acc[4]);
      acc[5] = fmaf(wv, bfh(cur.z), acc[5]);
      acc[6] = fmaf(wv, bfl(cur.w), acc[6]);
      acc[7] = fmaf(wv, bfh(cur.w), acc[7]);
    };
    int it = 0;
    while (it < itc) {
      body(v0, w0);
      if (it + 2 < itc) {
        int j = (it + 2) * EPI + sub;
        c0 = __shfl(myc, j, 64);
        w0 = __shfl(myw, j, 64);
        v0 = *(const uint4*)(xl + (size_t)c0 * F + base);
      }
      ++it;
      if (it >= itc) break;
      body(v1, w1);
      if (it + 2 < itc) {
        int j = (it + 2) * EPI + sub;
        c1 = __shfl(myc, j, 64);
        w1 = __shfl(myw, j, 64);
        v1 = *(const uint4*)(xl + (size_t)c1 * F + base);
      }
      ++it;
    }
  }

  // merge sub-slot partials (disjoint edges, same features)
#pragma unroll
  for (int off = LPE; off < 64; off <<= 1)
#pragma unroll
    for (int e = 0; e < 8; ++e) acc[e] += __shfl_xor(acc[e], off, 64);

  float inv = 1.f / (l + 1e-16f);
  if (sub == 0) {
    uint4 rv = *(const uint4*)(res + (size_t)node * F + base);
    float rs[8];
    rs[0] = bfl(rv.x); rs[1] = bfh(rv.x);
    rs[2] = bfl(rv.y); rs[3] = bfh(rv.y);
    rs[4] = bfl(rv.z); rs[5] = bfh(rv.z);
    rs[6] = bfl(rv.w); rs[7] = bfh(rv.w);
    float ov[8];
#pragma unroll
    for (int e = 0; e < 8; ++e) {
      float o = fmaf(acc[e], inv, rs[e]);
      if (ELU) o = (o > 0.f) ? o : (__expf(o) - 1.f);
      ov[e] = o;
    }
    if (OF32) {
      float* of = (float*)out;
#pragma unroll
      for (int e = 0; e < 8; ++e) of[(size_t)node * F + base + e] = ov[e];
    } else {
      u16* o16 = (u16*)out;
      uint4 pk;
      pk.x = (u32)f2bf(ov[0]) | ((u32)f2bf(ov[1]) << 16);
      pk.y = (u32)f2bf(ov[2]) | ((u32)f2bf(ov[3]) << 16);
      pk.z = (u32)f2bf(ov[4]) | ((u32)f2bf(ov[5]) << 16);
      pk.w = (u32)f2bf(ov[6]) | ((u32)f2bf(ov[7]) << 16);
      *(uint4*)(o16 + (size_t)node * F + base) = pk;
    }
  }
}

extern "C" void kernel_launch(void* const* d_in, const int* in_sizes, int n_in,
                              void* d_out, int out_size, void* d_ws, size_t ws_size,
                              hipStream_t stream) {
  const u16* x16 = (const u16*)d_in[0];
  const int* ei = (const int*)d_in[1];
  const int N = NN, E = NE;

  char* ws = (char*)d_ws;
  size_t off = 0;
  auto alloc = [&](size_t bytes) -> void* {
    void* p = (void*)(ws + off);
    off += (bytes + 255) & ~(size_t)255;
    return p;
  };
  int* flags = (int*)alloc(2 * 4);
  int* cnt = (int*)alloc((size_t)N * 4);
  int* rowptr = (int*)alloc((size_t)(N + 1) * 4);
  int* fillp = (int*)alloc((size_t)N * 4);
  int* colb = (int*)alloc((size_t)E * 4);
  int* dstc = (int*)alloc((size_t)E * 4);
  float* wedge = (float*)alloc((size_t)E * 4);
  int* excl = (int*)alloc((size_t)N * 4);
  int* bsum = (int*)alloc(256 * 4);
  int* boff = (int*)alloc(256 * 4);
  float* Aarr = (float*)alloc((size_t)N * 4);
  float* Barr = (float*)alloc((size_t)N * 4);
  u16* Wt1a = (u16*)alloc((size_t)128 * 128 * 2);
  u16* Wt1b = (u16*)alloc((size_t)128 * 128 * 2);
  u16* Wt1c = (u16*)alloc((size_t)128 * 128 * 2);
  u16* Wt2a = (u16*)alloc((size_t)256 * 128 * 2);
  u16* Wt2b = (u16*)alloc((size_t)256 * 128 * 2);
  u16* Wt2c = (u16*)alloc((size_t)256 * 128 * 2);
  u16* buf1 = (u16*)alloc((size_t)N * 256 * 2);
  u16* buf2 = (u16*)alloc((size_t)N * 256 * 2);
  u16* buf3 = (u16*)alloc((size_t)N * 256 * 2);
  u16* h1 = (u16*)alloc((size_t)N * 128 * 2);
  (void)ws_size; (void)n_in; (void)in_sizes; (void)out_size;

  int nb = (N + 255) / 256;

  probe_kernel<<<1, 256, 0, stream>>>(x16, ei, flags);
  hipMemsetAsync(cnt, 0, (size_t)N * 4, stream);
  count_kernel<<<(E + 255) / 256, 256, 0, stream>>>(ei, flags, cnt, E);
  scan_local<<<nb, 256, 0, stream>>>(cnt, excl, bsum, N);
  scan_totals<<<1, 256, 0, stream>>>(bsum, boff, nb);
  scan_add<<<nb, 256, 0, stream>>>(excl, boff, cnt, rowptr, fillp, N);
  fill_kernel<<<(E + 255) / 256, 256, 0, stream>>>(ei, flags, fillp, colb, dstc, E);
  transpose_w<<<dim3(128, 6), 256, 0, stream>>>(
      d_in[2], d_in[3], d_in[5], d_in[7], d_in[8], d_in[10],
      Wt1a, Wt1b, Wt1c, Wt2a, Wt2b, Wt2c, flags);

  int gx = (N + 63) / 64;
  int gn4 = (N + 3) / 4;
  // score grids: waves = ceil(E/EPI), blocks = ceil(waves/4)
  int sc1_blocks = (E / 4 + 3) / 4;   // F=128: EPI=4
  int sc2_blocks = (E / 2 + 3) / 4;   // F=256: EPI=2

  // Layer 1: 128 -> 128
  gemm3_mfma<<<dim3(gx, 3, 1), 256, 0, stream>>>(
      d_in[0], Wt1a, Wt1b, Wt1c, d_in[6], buf1, buf2, buf3, flags, 1, N, 128);
  ab_kernel<128><<<gn4, 256, 0, stream>>>(buf1, buf2, d_in[4], flags, Aarr, Barr, N);
  score_kernel<128, 16><<<sc1_blocks, 256, 0, stream>>>(
      buf1, buf2, d_in[4], Aarr, Barr, colb, dstc, wedge, flags, E);
  agg_kernel<128, 16, true><<<gn4, 256, 0, stream>>>(
      buf1, buf3, wedge, rowptr, colb, h1, flags, 0, N);
  // Layer 2: 128 -> 256
  gemm3_mfma<<<dim3(gx, 3, 2), 256, 0, stream>>>(
      h1, Wt2a, Wt2b, Wt2c, d_in[11], buf1, buf2, buf3, flags, 0, N, 256);
  ab_kernel<256><<<gn4, 256, 0, stream>>>(buf1, buf2, d_in[9], flags, Aarr, Barr, N);
  score_kernel<256, 32><<<sc2_blocks, 256, 0, stream>>>(
      buf1, buf2, d_in[9], Aarr, Barr, colb, dstc, wedge, flags, E);
  agg_kernel<256, 32, false><<<gn4, 256, 0, stream>>>(
      buf1, buf3, wedge, rowptr, colb, d_out, flags, 1, N);
}

// Round 7
// 522.170 us; speedup vs baseline: 1.5383x; 1.5383x over previous
//
#include <hip/hip_runtime.h>

typedef unsigned short u16;
typedef unsigned int u32;
typedef __attribute__((ext_vector_type(8))) short bf16x8;
typedef __attribute__((ext_vector_type(4))) float f32x4;

#define NN 50000
#define NE 640000

// ---- bf16 helpers (bf16 -> f32 exact: shift<<16; f32 -> bf16 RNE) ----
__device__ __forceinline__ float bfl(u32 u) { return __uint_as_float(u << 16); }
__device__ __forceinline__ float bfh(u32 u) { return __uint_as_float(u & 0xffff0000u); }
__device__ __forceinline__ float bf1(u16 v) { return __uint_as_float(((u32)v) << 16); }
__device__ __forceinline__ u16 f2bf(float f) {
  u32 u = __float_as_uint(f);
  u32 r = (u + 0x7fffu + ((u >> 16) & 1u)) >> 16;
  return (u16)r;
}

// ---------------- dtype probe ----------------
__global__ void probe_kernel(const u16* __restrict__ x, const int* __restrict__ ei,
                             int* __restrict__ flags) {
  __shared__ int s_f32, s_i32;
  if (threadIdx.x == 0) { s_f32 = 0; s_i32 = 0; }
  __syncthreads();
  int lf = 0, li = 0;
  for (int i = threadIdx.x; i < 8192; i += 256) {
    float v = bf1(x[i]);
    if (!(fabsf(v) < 1e8f)) lf = 1;
    if (ei[2 * i + 1] != 0) li = 1;
  }
  if (lf) s_f32 = 1;
  if (li) s_i32 = 1;
  __syncthreads();
  if (threadIdx.x == 0) {
    flags[0] = s_f32;
    flags[1] = s_i32 ? 0 : 1;
  }
}

// ---------------- CSR build ----------------
__device__ __forceinline__ int edge_val(const int* __restrict__ w, long j, int i64) {
  return i64 ? w[2 * j] : w[j];
}

__global__ void count_kernel(const int* __restrict__ ei, const int* __restrict__ flags,
                             int* __restrict__ cnt, int E) {
  int e = blockIdx.x * blockDim.x + threadIdx.x;
  if (e >= E) return;
  int d = edge_val(ei, (long)E + e, flags[1]);
  if ((u32)d < (u32)NN) atomicAdd(&cnt[d], 1);
}

__global__ void scan_local(const int* __restrict__ cnt, int* __restrict__ excl,
                           int* __restrict__ bsum, int n) {
  __shared__ int sd[256];
  int t = threadIdx.x;
  int g = blockIdx.x * 256 + t;
  int v = (g < n) ? cnt[g] : 0;
  sd[t] = v;
  __syncthreads();
  for (int off = 1; off < 256; off <<= 1) {
    int x = (t >= off) ? sd[t - off] : 0;
    __syncthreads();
    sd[t] += x;
    __syncthreads();
  }
  int incl = sd[t];
  if (g < n) excl[g] = incl - v;
  if (t == 255) bsum[blockIdx.x] = incl;
}

__global__ void scan_totals(const int* __restrict__ bsum, int* __restrict__ boff, int nb) {
  __shared__ int sd[256];
  int t = threadIdx.x;
  int v = (t < nb) ? bsum[t] : 0;
  sd[t] = v;
  __syncthreads();
  for (int off = 1; off < 256; off <<= 1) {
    int x = (t >= off) ? sd[t - off] : 0;
    __syncthreads();
    sd[t] += x;
    __syncthreads();
  }
  if (t < nb) boff[t] = sd[t] - v;
}

__global__ void scan_add(const int* __restrict__ excl, const int* __restrict__ boff,
                         const int* __restrict__ cnt, int* __restrict__ rowptr,
                         int* __restrict__ fillp, int n) {
  int g = blockIdx.x * 256 + threadIdx.x;
  if (g < n) {
    int e2 = excl[g] + boff[blockIdx.x];
    rowptr[g] = e2;
    fillp[g] = e2;
    if (g == n - 1) rowptr[n] = e2 + cnt[g];
  }
}

__global__ void fill_kernel(const int* __restrict__ ei, const int* __restrict__ flags,
                            int* __restrict__ fillp, int* __restrict__ col, int E) {
  int e = blockIdx.x * blockDim.x + threadIdx.x;
  if (e >= E) return;
  int i64 = flags[1];
  int s = edge_val(ei, (long)e, i64);
  int d = edge_val(ei, (long)E + e, i64);
  if ((u32)d >= (u32)NN) return;
  int p = atomicAdd(&fillp[d], 1);
  col[p] = ((u32)s < (u32)NN) ? s : 0;
}

// ---------------- weight pre-transpose: Wt[j][k] = W[k][j], output bf16 ----------------
__global__ void transpose_w(const void* W0, const void* W1, const void* W2,
                            const void* W3, const void* W4, const void* W5,
                            u16* T0, u16* T1, u16* T2, u16* T3, u16* T4, u16* T5,
                            const int* __restrict__ flags) {
  int y = blockIdx.y;
  int M = (y < 3) ? 128 : 256;
  int flat = blockIdx.x * 256 + threadIdx.x;
  if (flat >= M * 128) return;
  int j = flat >> 7;
  int k = flat & 127;
  const void* W = (y == 0) ? W0 : (y == 1) ? W1 : (y == 2) ? W2 : (y == 3) ? W3 : (y == 4) ? W4 : W5;
  u16* T = (y == 0) ? T0 : (y == 1) ? T1 : (y == 2) ? T2 : (y == 3) ? T3 : (y == 4) ? T4 : T5;
  u16 v;
  if (flags[0])
    v = f2bf(((const float*)W)[(size_t)k * M + j]);
  else
    v = ((const u16*)W)[(size_t)k * M + j];
  T[(size_t)j * 128 + k] = v;
}

// ---------------- MFMA GEMM + fused A/B attention dots ----------------
// Y{a,b,c}[n][j] = sum_k X[n][k]*W{a,b,c}[k][j] (+bias on c). K=128.
// y==0: also atomicAdd A[n] += att . Y-row-chunk; y==1: same into B.
#define LSTR 136
__global__ __launch_bounds__(256) void gemm3_mfma(
    const void* __restrict__ X,
    const u16* __restrict__ Wta, const u16* __restrict__ Wtb, const u16* __restrict__ Wtc,
    const void* __restrict__ bias, const void* __restrict__ att,
    float* __restrict__ Aarr, float* __restrict__ Barr,
    u16* __restrict__ Ya, u16* __restrict__ Yb, u16* __restrict__ Yc,
    const int* __restrict__ flags, int x_follows, int N, int M) {
  __shared__ __align__(16) u16 Xs[64 * LSTR];
  __shared__ __align__(16) u16 Bs[128 * LSTR];
  const int K = 128;
  int t = threadIdx.x;
  int lane = t & 63;
  int w = t >> 6;
  int n0g = blockIdx.x * 64;
  int c0 = blockIdx.z * 128;
  int F32 = flags[0];
  int F32X = x_follows ? F32 : 0;
  const u16* Wt = (blockIdx.y == 0) ? Wta : ((blockIdx.y == 1) ? Wtb : Wtc);
  u16* Y = (blockIdx.y == 0) ? Ya : ((blockIdx.y == 1) ? Yb : Yc);
  float* ABout = (blockIdx.y == 0) ? Aarr : Barr;

  if (!F32X) {
    const u16* Xg = (const u16*)X;
    for (int it = 0; it < 4; ++it) {
      int i = t + 256 * it;
      int r = i >> 4, c8 = (i & 15) * 8;
      int n = n0g + r;
      uint4 v = make_uint4(0, 0, 0, 0);
      if (n < N) v = *(const uint4*)(Xg + (size_t)n * K + c8);
      *(uint4*)(Xs + r * LSTR + c8) = v;
    }
  } else {
    const float* Xg = (const float*)X;
    for (int it = 0; it < 4; ++it) {
      int i = t + 256 * it;
      int r = i >> 4, c8 = (i & 15) * 8;
      int n = n0g + r;
      uint4 pk = make_uint4(0, 0, 0, 0);
      if (n < N) {
        float4 f0 = *(const float4*)(Xg + (size_t)n * K + c8);
        float4 f1 = *(const float4*)(Xg + (size_t)n * K + c8 + 4);
        pk.x = (u32)f2bf(f0.x) | ((u32)f2bf(f0.y) << 16);
        pk.y = (u32)f2bf(f0.z) | ((u32)f2bf(f0.w) << 16);
        pk.z = (u32)f2bf(f1.x) | ((u32)f2bf(f1.y) << 16);
        pk.w = (u32)f2bf(f1.z) | ((u32)f2bf(f1.w) << 16);
      }
      *(uint4*)(Xs + r * LSTR + c8) = pk;
    }
  }
  for (int it = 0; it < 8; ++it) {
    int i = t + 256 * it;
    int j = i >> 4, k8 = (i & 15) * 8;
    uint4 v = *(const uint4*)(Wt + (size_t)(c0 + j) * K + k8);
    *(uint4*)(Bs + j * LSTR + k8) = v;
  }
  __syncthreads();

  int m0 = (w >> 1) * 32;
  int n0 = (w & 1) * 64;
  int l15 = lane & 15;
  int q8 = (lane >> 4) * 8;
  f32x4 acc[2][4];
#pragma unroll
  for (int i = 0; i < 2; ++i)
#pragma unroll
    for (int j = 0; j < 4; ++j) acc[i][j] = (f32x4){0.f, 0.f, 0.f, 0.f};

#pragma unroll
  for (int kc = 0; kc < 4; ++kc) {
    int ko = kc * 32 + q8;
    bf16x8 a[2], b[4];
#pragma unroll
    for (int i = 0; i < 2; ++i)
      a[i] = *(const bf16x8*)(Xs + (m0 + i * 16 + l15) * LSTR + ko);
#pragma unroll
    for (int j = 0; j < 4; ++j)
      b[j] = *(const bf16x8*)(Bs + (n0 + j * 16 + l15) * LSTR + ko);
#pragma unroll
    for (int i = 0; i < 2; ++i)
#pragma unroll
      for (int j = 0; j < 4; ++j)
        acc[i][j] = __builtin_amdgcn_mfma_f32_16x16x32_bf16(a[i], b[j], acc[i][j], 0, 0, 0);
  }
  __syncthreads();

  float bv[4] = {0.f, 0.f, 0.f, 0.f};
  if (blockIdx.y == 2) {
#pragma unroll
    for (int j = 0; j < 4; ++j) {
      int c = c0 + n0 + j * 16 + l15;
      bv[j] = F32 ? ((const float*)bias)[c] : bf1(((const u16*)bias)[c]);
    }
  }

  u16* Ct = Xs;
#pragma unroll
  for (int i = 0; i < 2; ++i)
#pragma unroll
    for (int j = 0; j < 4; ++j) {
      int col = n0 + j * 16 + l15;
      int rbase = m0 + i * 16 + (lane >> 4) * 4;
#pragma unroll
      for (int r = 0; r < 4; ++r)
        Ct[(rbase + r) * LSTR + col] = f2bf(acc[i][j][r] + bv[j]);
    }
  __syncthreads();

  bool doAB = (blockIdx.y < 2);
  for (int it = 0; it < 4; ++it) {
    int i = t + 256 * it;
    int r = i >> 4, c8 = (i & 15) * 8;
    int n = n0g + r;
    uint4 v = *(const uint4*)(Ct + r * LSTR + c8);
    if (n < N) *(uint4*)(Y + (size_t)n * M + c0 + c8) = v;
    if (doAB) {
      float s = 0.f;
      float vv[8];
      vv[0] = bfl(v.x); vv[1] = bfh(v.x);
      vv[2] = bfl(v.y); vv[3] = bfh(v.y);
      vv[4] = bfl(v.z); vv[5] = bfh(v.z);
      vv[6] = bfl(v.w); vv[7] = bfh(v.w);
#pragma unroll
      for (int k = 0; k < 8; ++k) {
        float av = F32 ? ((const float*)att)[c0 + c8 + k] : bf1(((const u16*)att)[c0 + c8 + k]);
        s = fmaf(av, vv[k], s);
      }
      // reduce across the 16 lanes covering this row (lane-aligned group of 16)
#pragma unroll
      for (int off = 1; off <= 8; off <<= 1) s += __shfl_xor(s, off, 64);
      if ((i & 15) == 0 && n < N) atomicAdd(&ABout[n], s);
    }
  }
}

// ---------------- fused GATv2 aggregation: one wave per node, 4-deep gather pipeline ----
// LPE lanes per edge (LPE*8 == F), EPI = 64/LPE edges per iteration.
// score d = 0.6*(A[src]+B[dst]) + 0.4*sum(att*|xl+xr|); plain exp (scores O(+-12), f32-safe).
template <int F, int LPE, bool ELU>
__global__ __launch_bounds__(256) void agg_kernel(
    const u16* __restrict__ xl, const u16* __restrict__ xr, const u16* __restrict__ res,
    const void* __restrict__ att, const float* __restrict__ Aarr, const float* __restrict__ Barr,
    const int* __restrict__ rowptr, const int* __restrict__ col,
    void* __restrict__ out, const int* __restrict__ flags, int out_follows, int N) {
  constexpr int EPI = 64 / LPE;
  static_assert(LPE * 8 == F, "layout");
  int lane = threadIdx.x & 63;
  int sl = lane & (LPE - 1);
  int sub = lane / LPE;
  int node = blockIdx.x * 4 + (threadIdx.x >> 6);
  if (node >= N) return;
  int F32 = flags[0];
  int OF32 = out_follows ? F32 : 0;
  int base = sl * 8;

  float xrv[8], attv[8], acc[8];
  {
    uint4 ur = *(const uint4*)(xr + (size_t)node * F + base);
    xrv[0] = bfl(ur.x); xrv[1] = bfh(ur.x);
    xrv[2] = bfl(ur.y); xrv[3] = bfh(ur.y);
    xrv[4] = bfl(ur.z); xrv[5] = bfh(ur.z);
    xrv[6] = bfl(ur.w); xrv[7] = bfh(ur.w);
  }
#pragma unroll
  for (int e = 0; e < 8; ++e) {
    attv[e] = F32 ? ((const float*)att)[base + e] : bf1(((const u16*)att)[base + e]);
    acc[e] = 0.f;
  }
  float Bv = Barr[node];
  float l = 0.f;
  int beg = rowptr[node], end = rowptr[node + 1];

  for (int cs = beg; cs < end; cs += 64) {
    int n = min(64, end - cs);
    int idx = cs + lane;
    int myc = (idx < end) ? col[idx] : 0;
    float myA = (idx < end) ? Aarr[myc] : 0.f;
    int itc = (n + EPI - 1) / EPI;

    // 4-deep pipeline
    uint4 vbuf[4];
    float abuf[4];
#pragma unroll
    for (int p = 0; p < 4; ++p) {
      if (p < itc) {
        int j = p * EPI + sub;
        int c = __shfl(myc, j, 64);
        abuf[p] = __shfl(myA, j, 64);
        vbuf[p] = *(const uint4*)(xl + (size_t)c * F + base);
      }
    }
    for (int it = 0; it < itc; ++it) {
      uint4 cur = vbuf[it & 3];
      float aA = abuf[it & 3];
      if (it + 4 < itc) {
        int j = (it + 4) * EPI + sub;
        int c = __shfl(myc, j, 64);
        abuf[it & 3] = __shfl(myA, j, 64);
        vbuf[it & 3] = *(const uint4*)(xl + (size_t)c * F + base);
      }
      float xlv[8];
      xlv[0] = bfl(cur.x); xlv[1] = bfh(cur.x);
      xlv[2] = bfl(cur.y); xlv[3] = bfh(cur.y);
      xlv[4] = bfl(cur.z); xlv[5] = bfh(cur.z);
      xlv[6] = bfl(cur.w); xlv[7] = bfh(cur.w);
      float r = 0.f;
#pragma unroll
      for (int e = 0; e < 8; ++e) {
        float h = xlv[e] + xrv[e];
        r = fmaf(attv[e], fabsf(h), r);
      }
#pragma unroll
      for (int off = 1; off < LPE; off <<= 1) r += __shfl_xor(r, off, 64);
      float d = fmaf(0.4f, r, 0.6f * (aA + Bv));
      int act = (it * EPI + sub) < n;
      float wgt = act ? __expf(d) : 0.f;
      l += wgt;
#pragma unroll
      for (int e = 0; e < 8; ++e) acc[e] = fmaf(wgt, xlv[e], acc[e]);
    }
  }

  // merge sub-slot partials (disjoint edges, same features; lanes within sub duplicate)
#pragma unroll
  for (int off = LPE; off < 64; off <<= 1) {
    l += __shfl_xor(l, off, 64);
#pragma unroll
    for (int e = 0; e < 8; ++e) acc[e] += __shfl_xor(acc[e], off, 64);
  }

  float inv = 1.f / (l + 1e-16f);
  if (sub == 0) {
    uint4 rv = *(const uint4*)(res + (size_t)node * F + base);
    float rs[8];
    rs[0] = bfl(rv.x); rs[1] = bfh(rv.x);
    rs[2] = bfl(rv.y); rs[3] = bfh(rv.y);
    rs[4] = bfl(rv.z); rs[5] = bfh(rv.z);
    rs[6] = bfl(rv.w); rs[7] = bfh(rv.w);
    float ov[8];
#pragma unroll
    for (int e = 0; e < 8; ++e) {
      float o = fmaf(acc[e], inv, rs[e]);
      if (ELU) o = (o > 0.f) ? o : (__expf(o) - 1.f);
      ov[e] = o;
    }
    if (OF32) {
      float* of = (float*)out;
#pragma unroll
      for (int e = 0; e < 8; ++e) of[(size_t)node * F + base + e] = ov[e];
    } else {
      u16* o16 = (u16*)out;
      uint4 pk;
      pk.x = (u32)f2bf(ov[0]) | ((u32)f2bf(ov[1]) << 16);
      pk.y = (u32)f2bf(ov[2]) | ((u32)f2bf(ov[3]) << 16);
      pk.z = (u32)f2bf(ov[4]) | ((u32)f2bf(ov[5]) << 16);
      pk.w = (u32)f2bf(ov[6]) | ((u32)f2bf(ov[7]) << 16);
      *(uint4*)(o16 + (size_t)node * F + base) = pk;
    }
  }
}

extern "C" void kernel_launch(void* const* d_in, const int* in_sizes, int n_in,
                              void* d_out, int out_size, void* d_ws, size_t ws_size,
                              hipStream_t stream) {
  const u16* x16 = (const u16*)d_in[0];
  const int* ei = (const int*)d_in[1];
  const int N = NN, E = NE;

  char* ws = (char*)d_ws;
  size_t off = 0;
  auto alloc = [&](size_t bytes) -> void* {
    void* p = (void*)(ws + off);
    off += (bytes + 255) & ~(size_t)255;
    return p;
  };
  int* flags = (int*)alloc(2 * 4);
  int* cnt = (int*)alloc((size_t)N * 4);
  int* rowptr = (int*)alloc((size_t)(N + 1) * 4);
  int* fillp = (int*)alloc((size_t)N * 4);
  int* colb = (int*)alloc((size_t)E * 4);
  int* excl = (int*)alloc((size_t)N * 4);
  int* bsum = (int*)alloc(256 * 4);
  int* boff = (int*)alloc(256 * 4);
  float* Aarr = (float*)alloc((size_t)N * 4);
  float* Barr = (float*)alloc((size_t)N * 4);
  u16* Wt1a = (u16*)alloc((size_t)128 * 128 * 2);
  u16* Wt1b = (u16*)alloc((size_t)128 * 128 * 2);
  u16* Wt1c = (u16*)alloc((size_t)128 * 128 * 2);
  u16* Wt2a = (u16*)alloc((size_t)256 * 128 * 2);
  u16* Wt2b = (u16*)alloc((size_t)256 * 128 * 2);
  u16* Wt2c = (u16*)alloc((size_t)256 * 128 * 2);
  u16* buf1 = (u16*)alloc((size_t)N * 256 * 2);
  u16* buf2 = (u16*)alloc((size_t)N * 256 * 2);
  u16* buf3 = (u16*)alloc((size_t)N * 256 * 2);
  u16* h1 = (u16*)alloc((size_t)N * 128 * 2);
  (void)ws_size; (void)n_in; (void)in_sizes; (void)out_size;

  int nb = (N + 255) / 256;

  probe_kernel<<<1, 256, 0, stream>>>(x16, ei, flags);
  hipMemsetAsync(cnt, 0, (size_t)N * 4, stream);
  count_kernel<<<(E + 255) / 256, 256, 0, stream>>>(ei, flags, cnt, E);
  scan_local<<<nb, 256, 0, stream>>>(cnt, excl, bsum, N);
  scan_totals<<<1, 256, 0, stream>>>(bsum, boff, nb);
  scan_add<<<nb, 256, 0, stream>>>(excl, boff, cnt, rowptr, fillp, N);
  fill_kernel<<<(E + 255) / 256, 256, 0, stream>>>(ei, flags, fillp, colb, E);
  transpose_w<<<dim3(128, 6), 256, 0, stream>>>(
      d_in[2], d_in[3], d_in[5], d_in[7], d_in[8], d_in[10],
      Wt1a, Wt1b, Wt1c, Wt2a, Wt2b, Wt2c, flags);

  int gx = (N + 63) / 64;
  int gn4 = (N + 3) / 4;

  // Layer 1: 128 -> 128
  hipMemsetAsync(Aarr, 0, (size_t)N * 4, stream);
  hipMemsetAsync(Barr, 0, (size_t)N * 4, stream);
  gemm3_mfma<<<dim3(gx, 3, 1), 256, 0, stream>>>(
      d_in[0], Wt1a, Wt1b, Wt1c, d_in[6], d_in[4], Aarr, Barr,
      buf1, buf2, buf3, flags, 1, N, 128);
  agg_kernel<128, 16, true><<<gn4, 256, 0, stream>>>(
      buf1, buf2, buf3, d_in[4], Aarr, Barr, rowptr, colb, h1, flags, 0, N);

  // Layer 2: 128 -> 256
  hipMemsetAsync(Aarr, 0, (size_t)N * 4, stream);
  hipMemsetAsync(Barr, 0, (size_t)N * 4, stream);
  gemm3_mfma<<<dim3(gx, 3, 2), 256, 0, stream>>>(
      h1, Wt2a, Wt2b, Wt2c, d_in[11], d_in[9], Aarr, Barr,
      buf1, buf2, buf3, flags, 0, N, 256);
  agg_kernel<256, 32, false><<<gn4, 256, 0, stream>>>(
      buf1, buf2, buf3, d_in[9], Aarr, Barr, rowptr, colb, d_out, flags, 1, N);
}